// Round 2
// baseline (4242.010 us; speedup 1.0000x reference)
//
#include <hip/hip_runtime.h>
#include <stdint.h>

#define D 512
#define BATCH 32
#define TT 2048
#define BT (BATCH*TT)   // 65536

typedef unsigned short u16;
typedef __attribute__((ext_vector_type(8))) short bf16x8;
typedef __attribute__((ext_vector_type(4))) float f32x4;

__device__ __forceinline__ float bf2f(u16 u){
  union { unsigned int i; float f; } v; v.i = ((unsigned int)u) << 16; return v.f;
}
__device__ __forceinline__ u16 f2bf(float f){
  union { float f; unsigned int i; } v; v.f = f;
  unsigned int r = (v.i + 0x7fffu + ((v.i >> 16) & 1u)) >> 16;
  return (u16)r;
}

__device__ __forceinline__ int dot4i8(int a, int b, int c){
#if __has_builtin(__builtin_amdgcn_sdot4)
  return __builtin_amdgcn_sdot4(a, b, c, false);
#else
  c += (int)(char)(a      ) * (int)(char)(b      );
  c += (int)(char)(a >>  8) * (int)(char)(b >>  8);
  c += (int)(char)(a >> 16) * (int)(char)(b >> 16);
  c += (int)(char)(a >> 24) * (int)(char)(b >> 24);
  return c;
#endif
}

// ---------------- rmsnorm: xn = x/max(||x||,1e-12) * sqrt(D) * (gamma+1) ---
// x fp32 -> xn bf16 plane
__global__ __launch_bounds__(256) void rmsnorm_k(const float* __restrict__ x,
                                                 const float* __restrict__ gamma,
                                                 u16* __restrict__ xn){
  int row = blockIdx.x;
  int t = threadIdx.x;
  const float* xr = x + (size_t)row * D;
  float v0 = xr[t];
  float v1 = xr[t + 256];
  float s = v0*v0 + v1*v1;
  #pragma unroll
  for (int o = 32; o > 0; o >>= 1) s += __shfl_down(s, o);
  __shared__ float red[4];
  int lane = t & 63, wv = t >> 6;
  if (lane == 0) red[wv] = s;
  __syncthreads();
  float tot = red[0] + red[1] + red[2] + red[3];
  float n = fmaxf(sqrtf(tot), 1e-12f);
  float sc = 22.627416997969522f / n;   // sqrt(512)
  u16* o_ = xn + (size_t)row * D;
  o_[t]       = f2bf(v0 * sc * (gamma[t] + 1.f));
  o_[t + 256] = f2bf(v1 * sc * (gamma[t + 256] + 1.f));
}

// -------- 512x512 transpose + fp32->bf16 convert (dst[n][k] = src[k][n]) ---
__global__ __launch_bounds__(256) void transpose_k(const float* __restrict__ src,
                                                   u16* __restrict__ dst){
  __shared__ u16 tile[32][33];
  int bx = blockIdx.x * 32, by = blockIdx.y * 32;
  int tx = threadIdx.x & 31, ty = threadIdx.x >> 5;   // 32 x 8
  #pragma unroll
  for (int i = 0; i < 32; i += 8)
    tile[ty + i][tx] = f2bf(src[(size_t)(by + ty + i) * D + bx + tx]);
  __syncthreads();
  #pragma unroll
  for (int i = 0; i < 32; i += 8)
    dst[(size_t)(bx + ty + i) * D + by + tx] = tile[tx][ty + i];
}

// -------- per-column int8 quantization of Whf (fp32 in) -------------------
__global__ __launch_bounds__(64) void quant_col_k(const float* __restrict__ W,
                                                  int* __restrict__ Wq,
                                                  float* __restrict__ sc){
  int e = blockIdx.x;        // column index
  int lane = threadIdx.x;    // 64 lanes, each covers 8 d's
  float w[8];
  float m = 0.f;
  #pragma unroll
  for (int j = 0; j < 8; j++){
    w[j] = W[(size_t)(lane*8 + j) * D + e];
    m = fmaxf(m, fabsf(w[j]));
  }
  #pragma unroll
  for (int o = 32; o > 0; o >>= 1) m = fmaxf(m, __shfl_xor(m, o));
  float inv = (m > 0.f) ? (127.f / m) : 0.f;
  int q[8];
  #pragma unroll
  for (int j = 0; j < 8; j++){
    int v = __float2int_rn(w[j] * inv);
    v = v < -127 ? -127 : (v > 127 ? 127 : v);
    q[j] = v & 0xff;
  }
  int p0 = q[0] | (q[1] << 8) | (q[2] << 16) | (q[3] << 24);
  int p1 = q[4] | (q[5] << 8) | (q[6] << 16) | (q[7] << 24);
  Wq[e*128 + lane*2]     = p0;
  Wq[e*128 + lane*2 + 1] = p1;
  if (lane == 0) sc[e] = m / (127.f * 127.f);
}

// ---------------- bf16 GEMM: C[m][n] = sum_k A[m][k]*Bt[n][k] -------------
__global__ __launch_bounds__(256) void gemm_bt_k(const u16* __restrict__ A,
                                                 const u16* __restrict__ Bt,
                                                 u16* __restrict__ C,
                                                 int do_tanh){
  __shared__ __align__(16) u16 As[128*32];
  __shared__ __align__(16) u16 Bs[128*32];
  int tid = threadIdx.x;
  int bm = blockIdx.x, bn = blockIdx.y;
  int wv = tid >> 6, lane = tid & 63;
  int wm = (wv & 1) * 64, wn = (wv >> 1) * 64;
  int m0 = lane & 15, quad = lane >> 4;
  f32x4 acc[4][4];
  #pragma unroll
  for (int i = 0; i < 4; i++)
    #pragma unroll
    for (int j = 0; j < 4; j++){
      f32x4 z = {0.f, 0.f, 0.f, 0.f};
      acc[i][j] = z;
    }
  const size_t arow = (size_t)bm * 128;
  const size_t brow = (size_t)bn * 128;
  for (int k0 = 0; k0 < D; k0 += 32){
    __syncthreads();
    #pragma unroll
    for (int i = 0; i < 2; i++){
      int c = tid + 256*i;
      int r = c >> 2, ko = (c & 3) * 8;
      ((int4*)As)[c] = *(const int4*)(A  + (arow + r) * D + k0 + ko);
      ((int4*)Bs)[c] = *(const int4*)(Bt + (brow + r) * D + k0 + ko);
    }
    __syncthreads();
    bf16x8 af[4], bfr[4];
    #pragma unroll
    for (int i = 0; i < 4; i++){
      af[i]  = *(const bf16x8*)(As + (wm + i*16 + m0) * 32 + quad*8);
      bfr[i] = *(const bf16x8*)(Bs + (wn + i*16 + m0) * 32 + quad*8);
    }
    #pragma unroll
    for (int i = 0; i < 4; i++)
      #pragma unroll
      for (int j = 0; j < 4; j++)
        acc[i][j] = __builtin_amdgcn_mfma_f32_16x16x32_bf16(af[i], bfr[j], acc[i][j], 0, 0, 0);
  }
  #pragma unroll
  for (int i = 0; i < 4; i++)
    #pragma unroll
    for (int j = 0; j < 4; j++)
      #pragma unroll
      for (int r = 0; r < 4; r++){
        size_t row = arow + wm + i*16 + quad*4 + r;
        int col = bn*128 + wn + j*16 + m0;
        float v = acc[i][j][r];
        if (do_tanh) v = tanhf(v);
        C[row * D + col] = f2bf(v);
      }
}

// ---------------- sequential LRU scan, one block per batch element --------
// thread e owns output dim e; Whf column e lives int8-packed in 128 VGPRs.
// Writes H IN-PLACE over Nn (safe: each thread reads (t+1) before writing t,
// and only touches its own column e).
__global__ __launch_bounds__(512, 2) void lru_scan_k(u16* __restrict__ Nn,        // tanh(x@Wn), becomes H
                                                     const u16* __restrict__ Ff,  // x@Wif
                                                     const int* __restrict__ Wq,
                                                     const float* __restrict__ sc,
                                                     const float* __restrict__ bhf){
  int e = threadIdx.x;
  int b = blockIdx.x;
  int w[128];
  #pragma unroll
  for (int i = 0; i < 128; i++) w[i] = Wq[e*128 + i];
  float scale = sc[e];
  float bias  = bhf[e];
  __shared__ __align__(16) int hq[2][128];
  if (e < 128) hq[0][e] = 0;
  float h = 0.f;
  const size_t base = (size_t)b * TT * D + e;
  u16* np = Nn + base;
  const u16* fp = Ff + base;
  float nv = bf2f(np[0]);
  float fv = bf2f(fp[0]);
  __syncthreads();
  for (int t = 0; t < TT; t++){
    float nv_n = 0.f, fv_n = 0.f;
    if (t < TT - 1){
      nv_n = bf2f(np[(size_t)(t+1) * D]);
      fv_n = bf2f(fp[(size_t)(t+1) * D]);
    }
    const int* hb = hq[t & 1];
    int z = 0;
    #pragma unroll
    for (int i = 0; i < 32; i++){
      int4 hc = ((const int4*)hb)[i];     // broadcast ds_read_b128
      z = dot4i8(w[4*i+0], hc.x, z);
      z = dot4i8(w[4*i+1], hc.y, z);
      z = dot4i8(w[4*i+2], hc.z, z);
      z = dot4i8(w[4*i+3], hc.w, z);
    }
    float arg = (float)z * scale + bias + fv;
    float g = 1.f / (1.f + __expf(-arg));
    h = h + g * (nv - h);
    np[(size_t)t * D] = f2bf(h);          // overwrite Nn with H
    int q = __float2int_rn(h * 127.f);
    q = q < -127 ? -127 : (q > 127 ? 127 : q);
    ((char*)hq[(t+1) & 1])[e] = (char)q;
    nv = nv_n; fv = fv_n;
    __syncthreads();
  }
}

// ---------------- final gate_cell, pass 1: lru -> (in-place over Nng) -----
__global__ __launch_bounds__(256) void final1_k(const u16* __restrict__ xn,
                                                u16* __restrict__ Nng,        // tanh(h1@gWn), becomes lru
                                                const u16* __restrict__ Ffg,  // h1@gWif
                                                const u16* __restrict__ Ghf,  // xn@gWhf
                                                const float* __restrict__ gbhf){
  size_t i = (size_t)blockIdx.x * 256 + threadIdx.x;
  int e = (int)(i & (D - 1));
  float xnv = bf2f(xn[i]);
  float nv  = bf2f(Nng[i]);
  float arg = bf2f(Ghf[i]) + gbhf[e] + bf2f(Ffg[i]);
  float g = 1.f / (1.f + __expf(-arg));
  float lru = xnv + g * (nv - xnv);
  Nng[i] = f2bf(lru);
}

// ---------------- final pass 2: out = lru + x (fp32) ----------------------
__global__ __launch_bounds__(256) void final2_k(const u16* __restrict__ lru,
                                                const float* __restrict__ x,
                                                float* __restrict__ out){
  size_t i = (size_t)blockIdx.x * 256 + threadIdx.x;
  out[i] = bf2f(lru[i]) + x[i];
}

extern "C" void kernel_launch(void* const* d_in, const int* in_sizes, int n_in,
                              void* d_out, int out_size, void* d_ws, size_t ws_size,
                              hipStream_t stream){
  const float* x      = (const float*)d_in[0];
  const float* gamma  = (const float*)d_in[1];
  const float* g_Wn   = (const float*)d_in[2];
  const float* g_Wif  = (const float*)d_in[3];
  const float* g_Whf  = (const float*)d_in[4];
  const float* g_bhf  = (const float*)d_in[5];
  const float* l0_Wn  = (const float*)d_in[6];
  const float* l0_Wif = (const float*)d_in[7];
  const float* l0_Whf = (const float*)d_in[8];
  const float* l0_bhf = (const float*)d_in[9];
  const float* l1_Wn  = (const float*)d_in[10];
  const float* l1_Wif = (const float*)d_in[11];
  const float* l1_Whf = (const float*)d_in[12];
  const float* l1_bhf = (const float*)d_in[13];
  float* out = (float*)d_out;

  // ---- plane layout: P0,P1 in ws; P2,P3 inside d_out (2 bf16 planes = 134MB)
  char* ws = (char*)d_ws;
  const size_t PLANE = (size_t)BT * D * 2;      // 67.1 MB bf16 plane
  u16* P0 = (u16*)(ws);                         // xn (live to the end)
  u16* P1 = (u16*)(ws + PLANE);                 // Nn0/H0, then Nn_g, then lru
  u16* P2 = (u16*)d_out;                        // Ff planes
  u16* P3 = P2 + (size_t)BT * D;                // Nn1/H1, then Ghf

  char* wb = ws + 2*PLANE;
  const size_t WSZ = (size_t)D * D * 2;         // 512 KB per transposed bf16 weight
  u16* T_l0Wn  = (u16*)(wb + 0*WSZ);
  u16* T_l0Wif = (u16*)(wb + 1*WSZ);
  u16* T_gWhf  = (u16*)(wb + 2*WSZ);
  u16* T_l1Wn  = (u16*)(wb + 3*WSZ);
  u16* T_l1Wif = (u16*)(wb + 4*WSZ);
  u16* T_gWn   = (u16*)(wb + 5*WSZ);
  u16* T_gWif  = (u16*)(wb + 6*WSZ);
  int*   Wq0 = (int*)  (wb + 7*WSZ);
  int*   Wq1 = (int*)  (wb + 7*WSZ + (size_t)D*D);
  float* sc0 = (float*)(wb + 7*WSZ + 2*(size_t)D*D);
  float* sc1 = (float*)(wb + 7*WSZ + 2*(size_t)D*D + D*4);

  dim3 tb(256), tg(16, 16);
  // weight prep (tiny)
  transpose_k<<<tg, tb, 0, stream>>>(l0_Wn,  T_l0Wn);
  transpose_k<<<tg, tb, 0, stream>>>(l0_Wif, T_l0Wif);
  transpose_k<<<tg, tb, 0, stream>>>(g_Whf,  T_gWhf);
  transpose_k<<<tg, tb, 0, stream>>>(l1_Wn,  T_l1Wn);
  transpose_k<<<tg, tb, 0, stream>>>(l1_Wif, T_l1Wif);
  transpose_k<<<tg, tb, 0, stream>>>(g_Wn,   T_gWn);
  transpose_k<<<tg, tb, 0, stream>>>(g_Wif,  T_gWif);
  quant_col_k<<<512, 64, 0, stream>>>(l0_Whf, Wq0, sc0);
  quant_col_k<<<512, 64, 0, stream>>>(l1_Whf, Wq1, sc1);

  rmsnorm_k<<<BT, 256, 0, stream>>>(x, gamma, P0);

  dim3 gg(BT/128, D/128);
  // layer 0
  gemm_bt_k<<<gg, tb, 0, stream>>>(P0, T_l0Wn,  P1, 1);   // Nn0
  gemm_bt_k<<<gg, tb, 0, stream>>>(P0, T_l0Wif, P2, 0);   // Ff0
  lru_scan_k<<<BATCH, 512, 0, stream>>>(P1, P2, Wq0, sc0, l0_bhf);  // H0 -> P1
  // layer 1
  gemm_bt_k<<<gg, tb, 0, stream>>>(P1, T_l1Wn,  P3, 1);   // Nn1
  gemm_bt_k<<<gg, tb, 0, stream>>>(P1, T_l1Wif, P2, 0);   // Ff1
  lru_scan_k<<<BATCH, 512, 0, stream>>>(P3, P2, Wq1, sc1, l1_bhf);  // H1 -> P3
  // gate cell projections (H0 dead -> P1, Ff1 dead -> P2)
  gemm_bt_k<<<gg, tb, 0, stream>>>(P3, T_gWn,  P1, 1);    // Nn_g
  gemm_bt_k<<<gg, tb, 0, stream>>>(P3, T_gWif, P2, 0);    // Ff_g
  gemm_bt_k<<<gg, tb, 0, stream>>>(P0, T_gWhf, P3, 0);    // Ghf (H1 dead)

  final1_k<<<BT*D/256, 256, 0, stream>>>(P0, P1, P2, P3, g_bhf);  // lru -> P1
  final2_k<<<BT*D/256, 256, 0, stream>>>(P1, x, out);
}